// Round 5
// baseline (350.920 us; speedup 1.0000x reference)
//
#include <hip/hip_runtime.h>
#include <hip/hip_bf16.h>
#include <stdint.h>

// ---------------------------------------------------------------------------
// att_layer: out = softmax((q@Wq+bq)(k@Wk+bk)^T * scale) @ (v@Wv+bv) @ Wo + bo
// N=16384, IN=256, HID=128, OUT=256, fp32 in/out, bf16 MFMA internally.
//
// flash v5 = v4 + occupancy x2 (nsplit=8, 2 blocks/CU) + permlane32_swap
// P-assembly (T12, no DS crossbar) + bf16 Opart (fits proven ws floor).
// ---------------------------------------------------------------------------

#define N_TOK 16384
#define IN_DIM 256
#define HID 128
#define OUT_DIM 256
#define KVB 64
#define BM 256

typedef __bf16   bf16x8 __attribute__((ext_vector_type(8)));
typedef short    short8 __attribute__((ext_vector_type(8)));
typedef float    f32x4  __attribute__((ext_vector_type(4)));
typedef float    f32x16 __attribute__((ext_vector_type(16)));
typedef uint32_t u32x4  __attribute__((ext_vector_type(4)));

#define MFMA16(a,b,c) __builtin_amdgcn_mfma_f32_16x16x32_bf16((a),(b),(c),0,0,0)
#define MFMA32(a,b,c) __builtin_amdgcn_mfma_f32_32x32x16_bf16((a),(b),(c),0,0,0)
#define EXP2(x) __builtin_amdgcn_exp2f(x)

__device__ __forceinline__ short f2bf(float f) {
    union { float f; uint32_t u; } v; v.f = f;
    uint32_t r = v.u + 0x7FFFu + ((v.u >> 16) & 1u);   // RNE
    return (short)(r >> 16);
}

__device__ __forceinline__ uint32_t cvtpk(float lo, float hi) {
    uint32_t d;
    asm("v_cvt_pk_bf16_f32 %0, %1, %2" : "=v"(d) : "v"(lo), "v"(hi));
    return d;
}

// v_permlane32_swap_b32 via builtin: returns {vdst', src'} as a value pair —
// vdst' = {a.lanes[0:31], b.lanes[0:31]}, src' = {a.lanes[32:63], b.lanes[32:63]}
__device__ __forceinline__ void pswap(uint32_t& a, uint32_t& b) {
    auto r = __builtin_amdgcn_permlane32_swap(a, b, false, false);
    a = r[0]; b = r[1];
}

__device__ __forceinline__ void gl16(const void* g, const void* l) {
    __builtin_amdgcn_global_load_lds(
        (const __attribute__((address_space(1))) void*)g,
        (__attribute__((address_space(3))) void*)l, 16, 0, 0);
}

__device__ __forceinline__ float vmax16(f32x16 v) {
    float a = fmaxf(fmaxf(v[0], v[1]),  fmaxf(v[2], v[3]));
    float b = fmaxf(fmaxf(v[4], v[5]),  fmaxf(v[6], v[7]));
    float c = fmaxf(fmaxf(v[8], v[9]),  fmaxf(v[10], v[11]));
    float d = fmaxf(fmaxf(v[12], v[13]), fmaxf(v[14], v[15]));
    return fmaxf(fmaxf(a, b), fmaxf(c, d));
}

// ------------------------- weight transpose ------------------------------
__global__ void wt_kernel(const float* __restrict__ W, short* __restrict__ WT,
                          int K, int C) {
    int idx = blockIdx.x * 256 + threadIdx.x;
    if (idx >= K * C) return;
    int k = idx / C, c = idx % C;
    WT[c * K + k] = f2bf(W[idx]);
}

// ------------------------- projection ------------------------------------
__global__ __launch_bounds__(256) void proj_kernel(
    const float* __restrict__ X, const short* __restrict__ WT,
    const float* __restrict__ bias, short* __restrict__ Y,
    float post_scale, int transpose_out)
{
    const int lane = threadIdx.x & 63;
    const int wave = threadIdx.x >> 6;
    const int g = lane >> 4, c = lane & 15;
    const int rowbase = blockIdx.x * 64 + wave * 16;

    bf16x8 a[8];
    const float* xrow = X + (size_t)(rowbase + c) * IN_DIM;
#pragma unroll
    for (int kk = 0; kk < 8; ++kk) {
        const float* p = xrow + kk * 32 + 8 * g;
        float4 f0 = *(const float4*)(p);
        float4 f1 = *(const float4*)(p + 4);
        short8 t;
        t[0]=f2bf(f0.x); t[1]=f2bf(f0.y); t[2]=f2bf(f0.z); t[3]=f2bf(f0.w);
        t[4]=f2bf(f1.x); t[5]=f2bf(f1.y); t[6]=f2bf(f1.z); t[7]=f2bf(f1.w);
        a[kk] = __builtin_bit_cast(bf16x8, t);
    }

    f32x4 acc[8];
#pragma unroll
    for (int nf = 0; nf < 8; ++nf) acc[nf] = (f32x4){0.f, 0.f, 0.f, 0.f};

#pragma unroll
    for (int kk = 0; kk < 8; ++kk) {
#pragma unroll
        for (int nf = 0; nf < 8; ++nf) {
            bf16x8 b = *(const bf16x8*)(WT + (size_t)(c + 16 * nf) * IN_DIM + kk * 32 + 8 * g);
            acc[nf] = MFMA16(a[kk], b, acc[nf]);
        }
    }

#pragma unroll
    for (int nf = 0; nf < 8; ++nf) {
        int col = c + 16 * nf;
        float bval = bias[col];
#pragma unroll
        for (int r = 0; r < 4; ++r) {
            int row = rowbase + 4 * g + r;
            short val = f2bf((acc[nf][r] + bval) * post_scale);
            if (transpose_out) Y[(size_t)col * N_TOK + row] = val;
            else               Y[(size_t)row * HID + col] = val;
        }
    }
}

// ------------------------- flash attention v5 ----------------------------
// 512 thr (8 waves); wave owns 32 q-rows; KVB=64 keys/tile; 32x32x16 MFMA.
// nsplit=8 -> grid 512 -> 2 blocks/CU (128KB LDS), 4 waves/SIMD.
__global__ __launch_bounds__(512, 4) void flash_kernel(
    const short* __restrict__ qh, const short* __restrict__ kh,
    const short* __restrict__ vhT,
    short* __restrict__ Opart, float* __restrict__ Mpart, float* __restrict__ Lpart,
    int nsplit)
{
    __shared__ short K_lds[2][KVB * HID];   // [buf][key*128+d]  2x16KB, swizzled
    __shared__ short V_lds[2][HID * KVB];   // [buf][d*64+key]   2x16KB, swizzled

    const int tid  = threadIdx.x;
    const int lane = tid & 63;
    const int wave = tid >> 6;
    const int hi   = lane >> 5;
    const int col  = lane & 31;

    // XCD-aware decode: all blocks of an XCD share one KV split (L2-res.)
    const int lid = blockIdx.x;
    const int xcd = lid & 7, ib = lid >> 3;
    const int split = xcd % nsplit;
    const int qtile = ib + (8 * nsplit) * (xcd / nsplit);

    const int qb = qtile * BM + wave * 32;
    const int kvlen = N_TOK / nsplit;
    const int kv0 = split * kvlen;
    const int ntiles = kvlen / KVB;

    // Q B-frags: qf[kk] = qh[qb+col][16kk + 8hi + j]
    bf16x8 qf[8];
    const short* qrow = qh + (size_t)(qb + col) * HID + 8 * hi;
#pragma unroll
    for (int kk = 0; kk < 8; ++kk)
        qf[kk] = *(const bf16x8*)(qrow + 16 * kk);

    f32x16 o[4];
#pragma unroll
    for (int nf = 0; nf < 4; ++nf)
#pragma unroll
        for (int i = 0; i < 16; ++i) o[nf][i] = 0.f;
    float m_run = -1e30f, l_run = 0.f;   // log2 domain; l per half-lane

    // --- staging (pre-swizzled global source; LDS written linearly) ---
    const uint32_t L0 = (uint32_t)tid * 16;      // issue 0 byte
    const uint32_t L1 = L0 + 8192;               // issue 1 byte
    // K: row=L>>8 (256B rows), ch4=(L>>4)&15, src ch = ch4 ^ (row&7)
    const uint32_t kr0 = L0 >> 8, kc0 = ((L0 >> 4) & 15) ^ (kr0 & 7);
    const uint32_t kr1 = L1 >> 8, kc1 = ((L1 >> 4) & 15) ^ (kr1 & 7);
    // V: row d=L>>7 (128B rows), ch3=(L>>4)&7, src ch = ch3 ^ (d&7)
    const uint32_t vd0 = L0 >> 7, vc0 = ((L0 >> 4) & 7) ^ (vd0 & 7);
    const uint32_t vd1 = L1 >> 7, vc1 = ((L1 >> 4) & 7) ^ (vd1 & 7);
    const short* ks0 = kh + (size_t)(kv0 + kr0) * HID + kc0 * 8;
    const short* ks1 = kh + (size_t)(kv0 + kr1) * HID + kc1 * 8;
    const short* vs0 = vhT + (size_t)vd0 * N_TOK + kv0 + vc0 * 8;
    const short* vs1 = vhT + (size_t)vd1 * N_TOK + kv0 + vc1 * 8;

    auto stage = [&](int t, int buf) {
        gl16(ks0 + (size_t)t * (KVB * HID), &K_lds[buf][wave * 512]);
        gl16(ks1 + (size_t)t * (KVB * HID), &K_lds[buf][4096 + wave * 512]);
        gl16(vs0 + t * KVB, &V_lds[buf][wave * 512]);
        gl16(vs1 + t * KVB, &V_lds[buf][4096 + wave * 512]);
    };

    stage(0, 0);
    __syncthreads();

    for (int t = 0; t < ntiles; ++t) {
        const int cur = t & 1;
        if (t + 1 < ntiles) stage(t + 1, cur ^ 1);
        const short* Kc = &K_lds[cur][0];
        const short* Vc = &V_lds[cur][0];

        // ---- QK^T swapped: s0/s1 = S[key 0..31 / 32..63][q=col] ----
        f32x16 s0, s1;
#pragma unroll
        for (int i = 0; i < 16; ++i) { s0[i] = 0.f; s1[i] = 0.f; }
        __builtin_amdgcn_s_setprio(1);
#pragma unroll
        for (int kk = 0; kk < 8; ++kk) {
            const int sw = ((2 * kk + hi) ^ (col & 7)) << 3;
            bf16x8 ka0 = *(const bf16x8*)(Kc + col * HID + sw);
            bf16x8 ka1 = *(const bf16x8*)(Kc + (col + 32) * HID + sw);
            s0 = MFMA32(ka0, qf[kk], s0);
            s1 = MFMA32(ka1, qf[kk], s1);
        }
        __builtin_amdgcn_s_setprio(0);

        // ---- tile max: in-lane tree + cross-half permlane (alias-safe) ----
        float pm = fmaxf(vmax16(s0), vmax16(s1));
        {
            uint32_t ax = __builtin_bit_cast(uint32_t, pm), bx = ax;
            pswap(ax, bx);
            pm = fmaxf(__builtin_bit_cast(float, ax), __builtin_bit_cast(float, bx));
        }
        if (!__all(pm - m_run <= 11.0f)) {          // defer-max (T13)
            float mn = fmaxf(m_run, pm);
            float cf = EXP2(m_run - mn);
            l_run *= cf;
#pragma unroll
            for (int nf = 0; nf < 4; ++nf)
#pragma unroll
                for (int i = 0; i < 16; ++i) o[nf][i] *= cf;
            m_run = mn;
        }

        // ---- exp + in-register P->bf16 A-frags (T12: cvt_pk + permlane) ----
        // key of s-reg i: (i&3) + 8*(i>>2) + 4*hi. pa[ks] slot j <-> key
        // 16ks + 8hi + j. pswap(x0,x2): x0 <- {x0.lo,x2.lo} (slots 0-1),
        // x2 <- {x0.hi,x2.hi} (slots 4-5 -> wA[2]); matches v4's proven map.
        bf16x8 pa[4];
        float lacc = 0.f;
        auto process = [&](f32x16 sv, bf16x8& paA, bf16x8& paB) {
            float e[16];
#pragma unroll
            for (int i = 0; i < 16; ++i) e[i] = EXP2(sv[i] - m_run);
            lacc += (((e[0]+e[1])+(e[2]+e[3])) + ((e[4]+e[5])+(e[6]+e[7])))
                  + (((e[8]+e[9])+(e[10]+e[11])) + ((e[12]+e[13])+(e[14]+e[15])));
            uint32_t x0 = cvtpk(e[0], e[1]),   x1 = cvtpk(e[2], e[3]);
            uint32_t x2 = cvtpk(e[4], e[5]),   x3 = cvtpk(e[6], e[7]);
            uint32_t x4 = cvtpk(e[8], e[9]),   x5 = cvtpk(e[10], e[11]);
            uint32_t x6 = cvtpk(e[12], e[13]), x7 = cvtpk(e[14], e[15]);
            pswap(x0, x2);  pswap(x1, x3);
            pswap(x4, x6);  pswap(x5, x7);
            u32x4 wA, wB;
            wA[0] = x0; wA[1] = x1; wA[2] = x2; wA[3] = x3;
            wB[0] = x4; wB[1] = x5; wB[2] = x6; wB[3] = x7;
            paA = __builtin_bit_cast(bf16x8, wA);
            paB = __builtin_bit_cast(bf16x8, wB);
        };
        process(s0, pa[0], pa[1]);
        process(s1, pa[2], pa[3]);
        l_run += lacc;

        // ---- PV: O[q][d] += P[q][key] @ V[key][d] (B from V^T LDS) ----
        __builtin_amdgcn_s_setprio(1);
#pragma unroll
        for (int ks = 0; ks < 4; ++ks) {
            const int sw = ((2 * ks + hi) ^ (col & 7)) << 3;
#pragma unroll
            for (int nf = 0; nf < 4; ++nf) {
                bf16x8 vf = *(const bf16x8*)(Vc + (32 * nf + col) * KVB + sw);
                o[nf] = MFMA32(pa[ks], vf, o[nf]);
            }
        }
        __builtin_amdgcn_s_setprio(0);

        __syncthreads();   // all waves done reading cur; vmcnt drained
    }

    // ---- epilogue (bf16 Opart) ----
    {   // combine l across key-halves (alias-safe permlane)
        uint32_t ax = __builtin_bit_cast(uint32_t, l_run), bx = ax;
        pswap(ax, bx);
        l_run = __builtin_bit_cast(float, ax) + __builtin_bit_cast(float, bx);
    }
    const size_t sbase = (size_t)split * N_TOK + qb;
#pragma unroll
    for (int nf = 0; nf < 4; ++nf)
#pragma unroll
        for (int r = 0; r < 16; ++r) {
            int qr = (r & 3) + 8 * (r >> 2) + 4 * hi;
            Opart[(sbase + qr) * HID + 32 * nf + col] = f2bf(o[nf][r]);
        }
    if (lane < 32) {
        Mpart[sbase + col] = m_run;
        Lpart[sbase + col] = l_run;
    }
}

// ------------------------- split combine (bf16 Opart) --------------------
__global__ void combine_kernel(const short* __restrict__ Opart,
                               const float* __restrict__ Mpart,
                               const float* __restrict__ Lpart,
                               short* __restrict__ O, int nsplit)
{
    int idx = blockIdx.x * 256 + threadIdx.x;   // N*16 threads
    int row = idx >> 4;
    int d8 = (idx & 15) * 8;
    if (row >= N_TOK) return;
    float M = -1e30f;
    for (int s = 0; s < nsplit; ++s) M = fmaxf(M, Mpart[(size_t)s * N_TOK + row]);
    float denom = 0.f;
    float acc[8] = {0.f, 0.f, 0.f, 0.f, 0.f, 0.f, 0.f, 0.f};
    for (int s = 0; s < nsplit; ++s) {
        float w = EXP2(Mpart[(size_t)s * N_TOK + row] - M);   // log2 domain
        denom += w * Lpart[(size_t)s * N_TOK + row];
        bf16x8 vv = *(const bf16x8*)(Opart + ((size_t)s * N_TOK + row) * HID + d8);
#pragma unroll
        for (int j = 0; j < 8; ++j) acc[j] += w * (float)vv[j];
    }
    float inv = 1.0f / denom;
    short8 ov;
#pragma unroll
    for (int j = 0; j < 8; ++j) ov[j] = f2bf(acc[j] * inv);
    *(short8*)(O + (size_t)row * HID + d8) = ov;
}

// ------------------------- output projection -----------------------------
__global__ __launch_bounds__(256) void oproj_kernel(
    const short* __restrict__ O, const short* __restrict__ WoT,
    const float* __restrict__ bo, float* __restrict__ out)
{
    const int lane = threadIdx.x & 63;
    const int wave = threadIdx.x >> 6;
    const int g = lane >> 4, c = lane & 15;
    const int rowbase = blockIdx.x * 64 + wave * 16;

    bf16x8 a[4];
    const short* orow = O + (size_t)(rowbase + c) * HID;
#pragma unroll
    for (int kk = 0; kk < 4; ++kk)
        a[kk] = *(const bf16x8*)(orow + kk * 32 + 8 * g);

    f32x4 acc[16];
#pragma unroll
    for (int nf = 0; nf < 16; ++nf) acc[nf] = (f32x4){0.f, 0.f, 0.f, 0.f};

#pragma unroll
    for (int kk = 0; kk < 4; ++kk)
#pragma unroll
        for (int nf = 0; nf < 16; ++nf) {
            bf16x8 b = *(const bf16x8*)(WoT + (size_t)(c + 16 * nf) * HID + kk * 32 + 8 * g);
            acc[nf] = MFMA16(a[kk], b, acc[nf]);
        }

#pragma unroll
    for (int nf = 0; nf < 16; ++nf) {
        int col = c + 16 * nf;
        float bval = bo[col];
#pragma unroll
        for (int r = 0; r < 4; ++r)
            out[(size_t)(rowbase + 4 * g + r) * OUT_DIM + col] = acc[nf][r] + bval;
    }
}

// ------------------------- launch ----------------------------------------
extern "C" void kernel_launch(void* const* d_in, const int* in_sizes, int n_in,
                              void* d_out, int out_size, void* d_ws, size_t ws_size,
                              hipStream_t stream)
{
    (void)in_sizes; (void)n_in; (void)out_size;
    const float* q  = (const float*)d_in[0];
    const float* k  = (const float*)d_in[1];
    const float* v  = (const float*)d_in[2];
    const float* Wq = (const float*)d_in[3];
    const float* bq = (const float*)d_in[4];
    const float* Wk = (const float*)d_in[5];
    const float* bk = (const float*)d_in[6];
    const float* Wv = (const float*)d_in[7];
    const float* bvp= (const float*)d_in[8];
    const float* Wo = (const float*)d_in[9];
    const float* bo = (const float*)d_in[10];
    float* out = (float*)d_out;

    // ws need: 4 wt (256KB) + qh/kh/vhT (12.6MB, Ob aliases qh)
    //          + Opart bf16 (ns*4.19MB) + M/L (ns*128KB) + align slack
    auto need = [](int ns) -> size_t {
        return (size_t)(4 * 65536)
             + (size_t)3 * N_TOK * HID * 2
             + (size_t)ns * N_TOK * HID * 2
             + (size_t)ns * N_TOK * 8
             + (size_t)64 * 1024;
    };
    int nsplit = 8;
    if (ws_size < need(8)) nsplit = 4;
    if (ws_size < need(4)) nsplit = 2;
    if (ws_size < need(2)) nsplit = 1;

    char* base = (char*)d_ws;
    size_t off = 0;
    auto alloc = [&](size_t bytes) -> void* {
        void* p = base + off;
        off = (off + bytes + 255) & ~(size_t)255;
        return p;
    };
    short* wtq = (short*)alloc(128 * 256 * 2);
    short* wtk = (short*)alloc(128 * 256 * 2);
    short* wtv = (short*)alloc(128 * 256 * 2);
    short* wto = (short*)alloc(256 * 128 * 2);
    short* qh  = (short*)alloc((size_t)N_TOK * HID * 2);
    short* khb = (short*)alloc((size_t)N_TOK * HID * 2);
    short* vhT = (short*)alloc((size_t)N_TOK * HID * 2);
    short* Opart = (short*)alloc((size_t)nsplit * N_TOK * HID * 2);
    float* Mp  = (float*)alloc((size_t)nsplit * N_TOK * 4);
    float* Lp  = (float*)alloc((size_t)nsplit * N_TOK * 4);
    short* Ob  = qh;   // qh is dead after flash_kernel; reuse for combined O

    // 128^-0.5 * log2(e): logits land in log2 domain for exp2-based softmax
    const float SCALE_L2E = 0.088388347648318447f * 1.4426950408889634f;

    wt_kernel<<<128, 256, 0, stream>>>(Wq, wtq, 256, 128);
    wt_kernel<<<128, 256, 0, stream>>>(Wk, wtk, 256, 128);
    wt_kernel<<<128, 256, 0, stream>>>(Wv, wtv, 256, 128);
    wt_kernel<<<128, 256, 0, stream>>>(Wo, wto, 128, 256);

    proj_kernel<<<N_TOK / 64, 256, 0, stream>>>(q, wtq, bq, qh, SCALE_L2E, 0);
    proj_kernel<<<N_TOK / 64, 256, 0, stream>>>(k, wtk, bk, khb, 1.0f, 0);
    proj_kernel<<<N_TOK / 64, 256, 0, stream>>>(v, wtv, bvp, vhT, 1.0f, 1);

    flash_kernel<<<dim3((N_TOK / BM) * nsplit), 512, 0, stream>>>(
        qh, khb, vhT, Opart, Mp, Lp, nsplit);

    combine_kernel<<<(N_TOK * 16) / 256, 256, 0, stream>>>(Opart, Mp, Lp, Ob, nsplit);

    oproj_kernel<<<N_TOK / 64, 256, 0, stream>>>(Ob, wto, bo, out);
}

// Round 6
// 225.426 us; speedup vs baseline: 1.5567x; 1.5567x over previous
//
#include <hip/hip_runtime.h>
#include <hip/hip_bf16.h>
#include <stdint.h>

// ---------------------------------------------------------------------------
// att_layer: out = softmax((q@Wq+bq)(k@Wk+bk)^T * scale) @ (v@Wv+bv) @ Wo + bo
// N=16384, IN=256, HID=128, OUT=256, fp32 in/out, bf16 MFMA internally.
//
// flash v6 = r4's proven per-wave path, re-tiled for occupancy WITHOUT
// register starvation (r5 lesson: launch_bounds(512,4) -> 128-reg cap ->
// spill -> 855MB scratch traffic):
//   - 256-thr blocks (4 waves), BM=128, KVB=32 -> s-regs halved (~140 total)
//   - __launch_bounds__(256,3): 3 blocks/CU = 12 waves/CU, cap 170 regs
//   - nsplit=6 (uneven tile split) -> grid 768 = exactly 3 blocks/CU
//   - LDS 32KB/block (2-buf K 8KB + V 8KB), gl_lds w16, pre-swizzled source
// ---------------------------------------------------------------------------

#define N_TOK 16384
#define IN_DIM 256
#define HID 128
#define OUT_DIM 256
#define KVB 32
#define BM 128
#define TOT_TILES (N_TOK / KVB)

typedef __bf16   bf16x8 __attribute__((ext_vector_type(8)));
typedef short    short8 __attribute__((ext_vector_type(8)));
typedef float    f32x4  __attribute__((ext_vector_type(4)));
typedef float    f32x16 __attribute__((ext_vector_type(16)));
typedef uint32_t u32x4  __attribute__((ext_vector_type(4)));

#define MFMA16(a,b,c) __builtin_amdgcn_mfma_f32_16x16x32_bf16((a),(b),(c),0,0,0)
#define MFMA32(a,b,c) __builtin_amdgcn_mfma_f32_32x32x16_bf16((a),(b),(c),0,0,0)
#define EXP2(x) __builtin_amdgcn_exp2f(x)

__device__ __forceinline__ short f2bf(float f) {
    union { float f; uint32_t u; } v; v.f = f;
    uint32_t r = v.u + 0x7FFFu + ((v.u >> 16) & 1u);   // RNE
    return (short)(r >> 16);
}

__device__ __forceinline__ uint32_t cvtpk(float lo, float hi) {
    uint32_t d;
    asm("v_cvt_pk_bf16_f32 %0, %1, %2" : "=v"(d) : "v"(lo), "v"(hi));
    return d;
}

// v_permlane32_swap_b32 (builtin, value-pair return -> alias-safe):
// a' = {a.lanes[0:31], b.lanes[0:31]}, b' = {a.lanes[32:63], b.lanes[32:63]}
__device__ __forceinline__ void pswap(uint32_t& a, uint32_t& b) {
    auto r = __builtin_amdgcn_permlane32_swap(a, b, false, false);
    a = r[0]; b = r[1];
}

__device__ __forceinline__ void gl16(const void* g, const void* l) {
    __builtin_amdgcn_global_load_lds(
        (const __attribute__((address_space(1))) void*)g,
        (__attribute__((address_space(3))) void*)l, 16, 0, 0);
}

__device__ __forceinline__ float vmax16(f32x16 v) {
    float a = fmaxf(fmaxf(v[0], v[1]),  fmaxf(v[2], v[3]));
    float b = fmaxf(fmaxf(v[4], v[5]),  fmaxf(v[6], v[7]));
    float c = fmaxf(fmaxf(v[8], v[9]),  fmaxf(v[10], v[11]));
    float d = fmaxf(fmaxf(v[12], v[13]), fmaxf(v[14], v[15]));
    return fmaxf(fmaxf(a, b), fmaxf(c, d));
}

// ------------------------- weight transpose ------------------------------
__global__ void wt_kernel(const float* __restrict__ W, short* __restrict__ WT,
                          int K, int C) {
    int idx = blockIdx.x * 256 + threadIdx.x;
    if (idx >= K * C) return;
    int k = idx / C, c = idx % C;
    WT[c * K + k] = f2bf(W[idx]);
}

// ------------------------- projection ------------------------------------
__global__ __launch_bounds__(256) void proj_kernel(
    const float* __restrict__ X, const short* __restrict__ WT,
    const float* __restrict__ bias, short* __restrict__ Y,
    float post_scale, int transpose_out)
{
    const int lane = threadIdx.x & 63;
    const int wave = threadIdx.x >> 6;
    const int g = lane >> 4, c = lane & 15;
    const int rowbase = blockIdx.x * 64 + wave * 16;

    bf16x8 a[8];
    const float* xrow = X + (size_t)(rowbase + c) * IN_DIM;
#pragma unroll
    for (int kk = 0; kk < 8; ++kk) {
        const float* p = xrow + kk * 32 + 8 * g;
        float4 f0 = *(const float4*)(p);
        float4 f1 = *(const float4*)(p + 4);
        short8 t;
        t[0]=f2bf(f0.x); t[1]=f2bf(f0.y); t[2]=f2bf(f0.z); t[3]=f2bf(f0.w);
        t[4]=f2bf(f1.x); t[5]=f2bf(f1.y); t[6]=f2bf(f1.z); t[7]=f2bf(f1.w);
        a[kk] = __builtin_bit_cast(bf16x8, t);
    }

    f32x4 acc[8];
#pragma unroll
    for (int nf = 0; nf < 8; ++nf) acc[nf] = (f32x4){0.f, 0.f, 0.f, 0.f};

#pragma unroll
    for (int kk = 0; kk < 8; ++kk) {
#pragma unroll
        for (int nf = 0; nf < 8; ++nf) {
            bf16x8 b = *(const bf16x8*)(WT + (size_t)(c + 16 * nf) * IN_DIM + kk * 32 + 8 * g);
            acc[nf] = MFMA16(a[kk], b, acc[nf]);
        }
    }

#pragma unroll
    for (int nf = 0; nf < 8; ++nf) {
        int col = c + 16 * nf;
        float bval = bias[col];
#pragma unroll
        for (int r = 0; r < 4; ++r) {
            int row = rowbase + 4 * g + r;
            short val = f2bf((acc[nf][r] + bval) * post_scale);
            if (transpose_out) Y[(size_t)col * N_TOK + row] = val;
            else               Y[(size_t)row * HID + col] = val;
        }
    }
}

// ------------------------- flash attention v6 ----------------------------
// 256 thr (4 waves); wave owns 32 q-rows (BM=128); KVB=32 keys/tile.
// grid = 128 * nsplit (nsplit=6 -> 768 = 3 blocks/CU).
__global__ __launch_bounds__(256, 3) void flash_kernel(
    const short* __restrict__ qh, const short* __restrict__ kh,
    const short* __restrict__ vhT,
    short* __restrict__ Opart, float* __restrict__ Mpart, float* __restrict__ Lpart,
    int nsplit)
{
    __shared__ short K_lds[2][KVB * HID];   // [buf][key*128+d]  2x8KB, swizzled
    __shared__ short V_lds[2][HID * KVB];   // [buf][d*32+key]   2x8KB, swizzled

    const int tid  = threadIdx.x;
    const int lane = tid & 63;
    const int wave = tid >> 6;
    const int hi   = lane >> 5;
    const int col  = lane & 31;

    const int lid = blockIdx.x;
    const int split = lid >> 7;          // [0, nsplit)
    const int qtile = lid & 127;         // [0, 128)

    const int qb = qtile * BM + wave * 32;
    // uneven tile split: TOT_TILES = 512 over nsplit splits
    const int tbase = TOT_TILES / nsplit, trem = TOT_TILES % nsplit;
    const int ntiles = tbase + (split < trem ? 1 : 0);
    const int kv0 = (tbase * split + (split < trem ? split : trem)) * KVB;

    // Q B-frags: qf[kk] = qh[qb+col][16kk + 8hi + j]
    bf16x8 qf[8];
    const short* qrow = qh + (size_t)(qb + col) * HID + 8 * hi;
#pragma unroll
    for (int kk = 0; kk < 8; ++kk)
        qf[kk] = *(const bf16x8*)(qrow + 16 * kk);

    f32x16 o[4];
#pragma unroll
    for (int nf = 0; nf < 4; ++nf)
#pragma unroll
        for (int i = 0; i < 16; ++i) o[nf][i] = 0.f;
    float m_run = -1e30f, l_run = 0.f;   // log2 domain; l per half-lane

    // --- staging (pre-swizzled global source; LDS written linearly) ---
    const uint32_t L0 = (uint32_t)tid * 16;      // issue 0 byte [0,4096)
    const uint32_t L1 = L0 + 4096;               // issue 1 byte [4096,8192)
    // K: row=L>>8 (256B rows, 16 chunks), src ch = ch ^ (row&7)
    const uint32_t kr0 = L0 >> 8, kc0 = ((L0 >> 4) & 15) ^ (kr0 & 7);
    const uint32_t kr1 = L1 >> 8, kc1 = ((L1 >> 4) & 15) ^ (kr1 & 7);
    // V: row d=L>>6 (64B rows, 4 chunks), src ch = ch ^ (d&3)
    const uint32_t vd0 = L0 >> 6, vc0 = ((L0 >> 4) & 3) ^ (vd0 & 3);
    const uint32_t vd1 = L1 >> 6, vc1 = ((L1 >> 4) & 3) ^ (vd1 & 3);
    const short* ks0 = kh + (size_t)(kv0 + kr0) * HID + kc0 * 8;
    const short* ks1 = kh + (size_t)(kv0 + kr1) * HID + kc1 * 8;
    const short* vs0 = vhT + (size_t)vd0 * N_TOK + kv0 + vc0 * 8;
    const short* vs1 = vhT + (size_t)vd1 * N_TOK + kv0 + vc1 * 8;

    auto stage = [&](int t, int buf) {
        gl16(ks0 + (size_t)t * (KVB * HID), &K_lds[buf][wave * 512]);
        gl16(ks1 + (size_t)t * (KVB * HID), &K_lds[buf][2048 + wave * 512]);
        gl16(vs0 + t * KVB, &V_lds[buf][wave * 512]);
        gl16(vs1 + t * KVB, &V_lds[buf][2048 + wave * 512]);
    };

    stage(0, 0);
    __syncthreads();

    for (int t = 0; t < ntiles; ++t) {
        const int cur = t & 1;
        if (t + 1 < ntiles) stage(t + 1, cur ^ 1);
        const short* Kc = &K_lds[cur][0];
        const short* Vc = &V_lds[cur][0];

        // ---- QK^T swapped: s0 = S[key 0..31][q=col] ----
        f32x16 s0;
#pragma unroll
        for (int i = 0; i < 16; ++i) s0[i] = 0.f;
        __builtin_amdgcn_s_setprio(1);
#pragma unroll
        for (int kk = 0; kk < 8; ++kk) {
            const int sw = ((2 * kk + hi) ^ (col & 7)) << 3;
            bf16x8 ka0 = *(const bf16x8*)(Kc + col * HID + sw);
            s0 = MFMA32(ka0, qf[kk], s0);
        }
        __builtin_amdgcn_s_setprio(0);

        // ---- tile max: in-lane tree + cross-half permlane ----
        float pm = vmax16(s0);
        {
            uint32_t ax = __builtin_bit_cast(uint32_t, pm), bx = ax;
            pswap(ax, bx);
            pm = fmaxf(__builtin_bit_cast(float, ax), __builtin_bit_cast(float, bx));
        }
        if (!__all(pm - m_run <= 11.0f)) {          // defer-max (T13)
            float mn = fmaxf(m_run, pm);
            float cf = EXP2(m_run - mn);
            l_run *= cf;
#pragma unroll
            for (int nf = 0; nf < 4; ++nf)
#pragma unroll
                for (int i = 0; i < 16; ++i) o[nf][i] *= cf;
            m_run = mn;
        }

        // ---- exp + in-register P->bf16 A-frags (T12) ----
        bf16x8 pa[2];
        {
            float e[16];
#pragma unroll
            for (int i = 0; i < 16; ++i) e[i] = EXP2(s0[i] - m_run);
            l_run += (((e[0]+e[1])+(e[2]+e[3])) + ((e[4]+e[5])+(e[6]+e[7])))
                   + (((e[8]+e[9])+(e[10]+e[11])) + ((e[12]+e[13])+(e[14]+e[15])));
            uint32_t x0 = cvtpk(e[0], e[1]),   x1 = cvtpk(e[2], e[3]);
            uint32_t x2 = cvtpk(e[4], e[5]),   x3 = cvtpk(e[6], e[7]);
            uint32_t x4 = cvtpk(e[8], e[9]),   x5 = cvtpk(e[10], e[11]);
            uint32_t x6 = cvtpk(e[12], e[13]), x7 = cvtpk(e[14], e[15]);
            pswap(x0, x2);  pswap(x1, x3);
            pswap(x4, x6);  pswap(x5, x7);
            u32x4 wA, wB;
            wA[0] = x0; wA[1] = x1; wA[2] = x2; wA[3] = x3;
            wB[0] = x4; wB[1] = x5; wB[2] = x6; wB[3] = x7;
            pa[0] = __builtin_bit_cast(bf16x8, wA);
            pa[1] = __builtin_bit_cast(bf16x8, wB);
        }

        // ---- PV: O[q][d] += P[q][key] @ V[key][d] (B from V^T LDS) ----
        __builtin_amdgcn_s_setprio(1);
#pragma unroll
        for (int ks = 0; ks < 2; ++ks) {
            const int sw = ((2 * ks + hi) ^ (col & 3)) << 3;
#pragma unroll
            for (int nf = 0; nf < 4; ++nf) {
                bf16x8 vf = *(const bf16x8*)(Vc + (32 * nf + col) * KVB + sw);
                o[nf] = MFMA32(pa[ks], vf, o[nf]);
            }
        }
        __builtin_amdgcn_s_setprio(0);

        __syncthreads();   // all waves done reading cur; vmcnt drained
    }

    // ---- epilogue (bf16 Opart) ----
    {   // combine l across key-halves
        uint32_t ax = __builtin_bit_cast(uint32_t, l_run), bx = ax;
        pswap(ax, bx);
        l_run = __builtin_bit_cast(float, ax) + __builtin_bit_cast(float, bx);
    }
    const size_t sbase = (size_t)split * N_TOK + qb;
#pragma unroll
    for (int nf = 0; nf < 4; ++nf)
#pragma unroll
        for (int r = 0; r < 16; ++r) {
            int qr = (r & 3) + 8 * (r >> 2) + 4 * hi;
            Opart[(sbase + qr) * HID + 32 * nf + col] = f2bf(o[nf][r]);
        }
    if (lane < 32) {
        Mpart[sbase + col] = m_run;
        Lpart[sbase + col] = l_run;
    }
}

// ------------------------- split combine (bf16 Opart) --------------------
__global__ void combine_kernel(const short* __restrict__ Opart,
                               const float* __restrict__ Mpart,
                               const float* __restrict__ Lpart,
                               short* __restrict__ O, int nsplit)
{
    int idx = blockIdx.x * 256 + threadIdx.x;   // N*16 threads
    int row = idx >> 4;
    int d8 = (idx & 15) * 8;
    if (row >= N_TOK) return;
    float M = -1e30f;
    for (int s = 0; s < nsplit; ++s) M = fmaxf(M, Mpart[(size_t)s * N_TOK + row]);
    float denom = 0.f;
    float acc[8] = {0.f, 0.f, 0.f, 0.f, 0.f, 0.f, 0.f, 0.f};
    for (int s = 0; s < nsplit; ++s) {
        float w = EXP2(Mpart[(size_t)s * N_TOK + row] - M);   // log2 domain
        denom += w * Lpart[(size_t)s * N_TOK + row];
        bf16x8 vv = *(const bf16x8*)(Opart + ((size_t)s * N_TOK + row) * HID + d8);
#pragma unroll
        for (int j = 0; j < 8; ++j) acc[j] += w * (float)vv[j];
    }
    float inv = 1.0f / denom;
    short8 ov;
#pragma unroll
    for (int j = 0; j < 8; ++j) ov[j] = f2bf(acc[j] * inv);
    *(short8*)(O + (size_t)row * HID + d8) = ov;
}

// ------------------------- output projection -----------------------------
__global__ __launch_bounds__(256) void oproj_kernel(
    const short* __restrict__ O, const short* __restrict__ WoT,
    const float* __restrict__ bo, float* __restrict__ out)
{
    const int lane = threadIdx.x & 63;
    const int wave = threadIdx.x >> 6;
    const int g = lane >> 4, c = lane & 15;
    const int rowbase = blockIdx.x * 64 + wave * 16;

    bf16x8 a[4];
    const short* orow = O + (size_t)(rowbase + c) * HID;
#pragma unroll
    for (int kk = 0; kk < 4; ++kk)
        a[kk] = *(const bf16x8*)(orow + kk * 32 + 8 * g);

    f32x4 acc[16];
#pragma unroll
    for (int nf = 0; nf < 16; ++nf) acc[nf] = (f32x4){0.f, 0.f, 0.f, 0.f};

#pragma unroll
    for (int kk = 0; kk < 4; ++kk)
#pragma unroll
        for (int nf = 0; nf < 16; ++nf) {
            bf16x8 b = *(const bf16x8*)(WoT + (size_t)(c + 16 * nf) * HID + kk * 32 + 8 * g);
            acc[nf] = MFMA16(a[kk], b, acc[nf]);
        }

#pragma unroll
    for (int nf = 0; nf < 16; ++nf) {
        int col = c + 16 * nf;
        float bval = bo[col];
#pragma unroll
        for (int r = 0; r < 4; ++r)
            out[(size_t)(rowbase + 4 * g + r) * OUT_DIM + col] = acc[nf][r] + bval;
    }
}

// ------------------------- launch ----------------------------------------
extern "C" void kernel_launch(void* const* d_in, const int* in_sizes, int n_in,
                              void* d_out, int out_size, void* d_ws, size_t ws_size,
                              hipStream_t stream)
{
    (void)in_sizes; (void)n_in; (void)out_size;
    const float* q  = (const float*)d_in[0];
    const float* k  = (const float*)d_in[1];
    const float* v  = (const float*)d_in[2];
    const float* Wq = (const float*)d_in[3];
    const float* bq = (const float*)d_in[4];
    const float* Wk = (const float*)d_in[5];
    const float* bk = (const float*)d_in[6];
    const float* Wv = (const float*)d_in[7];
    const float* bvp= (const float*)d_in[8];
    const float* Wo = (const float*)d_in[9];
    const float* bo = (const float*)d_in[10];
    float* out = (float*)d_out;

    auto need = [](int ns) -> size_t {
        return (size_t)(4 * 65536)
             + (size_t)3 * N_TOK * HID * 2
             + (size_t)ns * N_TOK * HID * 2
             + (size_t)ns * N_TOK * 8
             + (size_t)64 * 1024;
    };
    int nsplit = 6;
    if (ws_size < need(6)) nsplit = 4;
    if (ws_size < need(4)) nsplit = 2;
    if (ws_size < need(2)) nsplit = 1;

    char* base = (char*)d_ws;
    size_t off = 0;
    auto alloc = [&](size_t bytes) -> void* {
        void* p = base + off;
        off = (off + bytes + 255) & ~(size_t)255;
        return p;
    };
    short* wtq = (short*)alloc(128 * 256 * 2);
    short* wtk = (short*)alloc(128 * 256 * 2);
    short* wtv = (short*)alloc(128 * 256 * 2);
    short* wto = (short*)alloc(256 * 128 * 2);
    short* qh  = (short*)alloc((size_t)N_TOK * HID * 2);
    short* khb = (short*)alloc((size_t)N_TOK * HID * 2);
    short* vhT = (short*)alloc((size_t)N_TOK * HID * 2);
    short* Opart = (short*)alloc((size_t)nsplit * N_TOK * HID * 2);
    float* Mp  = (float*)alloc((size_t)nsplit * N_TOK * 4);
    float* Lp  = (float*)alloc((size_t)nsplit * N_TOK * 4);
    short* Ob  = qh;   // qh is dead after flash_kernel; reuse for combined O

    // 128^-0.5 * log2(e): logits land in log2 domain for exp2-based softmax
    const float SCALE_L2E = 0.088388347648318447f * 1.4426950408889634f;

    wt_kernel<<<128, 256, 0, stream>>>(Wq, wtq, 256, 128);
    wt_kernel<<<128, 256, 0, stream>>>(Wk, wtk, 256, 128);
    wt_kernel<<<128, 256, 0, stream>>>(Wv, wtv, 256, 128);
    wt_kernel<<<128, 256, 0, stream>>>(Wo, wto, 128, 256);

    proj_kernel<<<N_TOK / 64, 256, 0, stream>>>(q, wtq, bq, qh, SCALE_L2E, 0);
    proj_kernel<<<N_TOK / 64, 256, 0, stream>>>(k, wtk, bk, khb, 1.0f, 0);
    proj_kernel<<<N_TOK / 64, 256, 0, stream>>>(v, wtv, bvp, vhT, 1.0f, 1);

    flash_kernel<<<dim3(128 * nsplit), 256, 0, stream>>>(
        qh, khb, vhT, Opart, Mp, Lp, nsplit);

    combine_kernel<<<(N_TOK * 16) / 256, 256, 0, stream>>>(Opart, Mp, Lp, Ob, nsplit);

    oproj_kernel<<<N_TOK / 64, 256, 0, stream>>>(Ob, wto, bo, out);
}

// Round 7
// 201.639 us; speedup vs baseline: 1.7403x; 1.1180x over previous
//
#include <hip/hip_runtime.h>
#include <hip/hip_bf16.h>
#include <stdint.h>

// ---------------------------------------------------------------------------
// att_layer: out = softmax((q@Wq+bq)(k@Wk+bk)^T * scale) @ (v@Wv+bv) @ Wo + bo
// N=16384, IN=256, HID=128, OUT=256, fp32 in/out, bf16 MFMA internally.
//
// v7 = v6 +
//   - V LDS re-pack: [64 vrow=d>>1][128B] rows, 3-bit XOR swizzle (kills the
//     64B-row 2-way bank conflicts of v6's V layout)
//   - triple-buffer LDS + 2-deep prefetch + counted vmcnt(4) (T4: never
//     drain prefetch queue at the per-tile barrier)
//   - kernel fusion: wt x4 -> 1 launch, proj x3 -> 1 launch (grid.y),
//     combine folded into oproj (in-register LSE merge)
// ---------------------------------------------------------------------------

#define N_TOK 16384
#define IN_DIM 256
#define HID 128
#define OUT_DIM 256
#define KVB 32
#define BM 128
#define TOT_TILES (N_TOK / KVB)

typedef __bf16   bf16x8 __attribute__((ext_vector_type(8)));
typedef short    short8 __attribute__((ext_vector_type(8)));
typedef float    f32x4  __attribute__((ext_vector_type(4)));
typedef float    f32x16 __attribute__((ext_vector_type(16)));
typedef uint32_t u32x4  __attribute__((ext_vector_type(4)));

#define MFMA16(a,b,c) __builtin_amdgcn_mfma_f32_16x16x32_bf16((a),(b),(c),0,0,0)
#define MFMA32(a,b,c) __builtin_amdgcn_mfma_f32_32x32x16_bf16((a),(b),(c),0,0,0)
#define EXP2(x) __builtin_amdgcn_exp2f(x)

__device__ __forceinline__ short f2bf(float f) {
    union { float f; uint32_t u; } v; v.f = f;
    uint32_t r = v.u + 0x7FFFu + ((v.u >> 16) & 1u);   // RNE
    return (short)(r >> 16);
}

__device__ __forceinline__ uint32_t cvtpk(float lo, float hi) {
    uint32_t d;
    asm("v_cvt_pk_bf16_f32 %0, %1, %2" : "=v"(d) : "v"(lo), "v"(hi));
    return d;
}

// v_permlane32_swap_b32 (builtin, value-pair return -> alias-safe)
__device__ __forceinline__ void pswap(uint32_t& a, uint32_t& b) {
    auto r = __builtin_amdgcn_permlane32_swap(a, b, false, false);
    a = r[0]; b = r[1];
}

__device__ __forceinline__ void gl16(const void* g, const void* l) {
    __builtin_amdgcn_global_load_lds(
        (const __attribute__((address_space(1))) void*)g,
        (__attribute__((address_space(3))) void*)l, 16, 0, 0);
}

__device__ __forceinline__ float vmax16(f32x16 v) {
    float a = fmaxf(fmaxf(v[0], v[1]),  fmaxf(v[2], v[3]));
    float b = fmaxf(fmaxf(v[4], v[5]),  fmaxf(v[6], v[7]));
    float c = fmaxf(fmaxf(v[8], v[9]),  fmaxf(v[10], v[11]));
    float d = fmaxf(fmaxf(v[12], v[13]), fmaxf(v[14], v[15]));
    return fmaxf(fmaxf(a, b), fmaxf(c, d));
}

// ------------------- weight transpose (all 4 in one launch) ---------------
__global__ void wt4_kernel(const float* __restrict__ Wq, const float* __restrict__ Wk,
                           const float* __restrict__ Wv, const float* __restrict__ Wo,
                           short* __restrict__ tq, short* __restrict__ tk,
                           short* __restrict__ tv, short* __restrict__ to_)
{
    int idx = blockIdx.x * 256 + threadIdx.x;      // 4 x 32768
    int w = idx >> 15, i = idx & 32767;
    if (w < 3) {                                   // [256][128] -> [128][256]
        const float* W = (w == 0) ? Wq : (w == 1) ? Wk : Wv;
        short* T = (w == 0) ? tq : (w == 1) ? tk : tv;
        int k = i >> 7, c = i & 127;
        T[c * 256 + k] = f2bf(W[i]);
    } else {                                       // [128][256] -> [256][128]
        int k = i >> 8, c = i & 255;
        to_[c * 128 + k] = f2bf(Wo[i]);
    }
}

// ------------------- projection (q/k/v via blockIdx.y) --------------------
__global__ __launch_bounds__(256) void proj3_kernel(
    const float* __restrict__ q, const float* __restrict__ k, const float* __restrict__ v,
    const short* __restrict__ tq, const short* __restrict__ tk, const short* __restrict__ tv,
    const float* __restrict__ bq, const float* __restrict__ bk, const float* __restrict__ bv,
    short* __restrict__ qh, short* __restrict__ kh, short* __restrict__ vhT,
    float scale_q)
{
    const int y = blockIdx.y;
    const float* X  = (y == 0) ? q  : (y == 1) ? k  : v;
    const short* WT = (y == 0) ? tq : (y == 1) ? tk : tv;
    const float* bias = (y == 0) ? bq : (y == 1) ? bk : bv;
    short* Y = (y == 0) ? qh : (y == 1) ? kh : vhT;
    const float post_scale = (y == 0) ? scale_q : 1.0f;
    const int transpose_out = (y == 2);

    const int lane = threadIdx.x & 63;
    const int wave = threadIdx.x >> 6;
    const int g = lane >> 4, c = lane & 15;
    const int rowbase = blockIdx.x * 64 + wave * 16;

    bf16x8 a[8];
    const float* xrow = X + (size_t)(rowbase + c) * IN_DIM;
#pragma unroll
    for (int kk = 0; kk < 8; ++kk) {
        const float* p = xrow + kk * 32 + 8 * g;
        float4 f0 = *(const float4*)(p);
        float4 f1 = *(const float4*)(p + 4);
        short8 t;
        t[0]=f2bf(f0.x); t[1]=f2bf(f0.y); t[2]=f2bf(f0.z); t[3]=f2bf(f0.w);
        t[4]=f2bf(f1.x); t[5]=f2bf(f1.y); t[6]=f2bf(f1.z); t[7]=f2bf(f1.w);
        a[kk] = __builtin_bit_cast(bf16x8, t);
    }

    f32x4 acc[8];
#pragma unroll
    for (int nf = 0; nf < 8; ++nf) acc[nf] = (f32x4){0.f, 0.f, 0.f, 0.f};

#pragma unroll
    for (int kk = 0; kk < 8; ++kk) {
#pragma unroll
        for (int nf = 0; nf < 8; ++nf) {
            bf16x8 b = *(const bf16x8*)(WT + (size_t)(c + 16 * nf) * IN_DIM + kk * 32 + 8 * g);
            acc[nf] = MFMA16(a[kk], b, acc[nf]);
        }
    }

#pragma unroll
    for (int nf = 0; nf < 8; ++nf) {
        int col = c + 16 * nf;
        float bval = bias[col];
#pragma unroll
        for (int r = 0; r < 4; ++r) {
            int row = rowbase + 4 * g + r;
            short val = f2bf((acc[nf][r] + bval) * post_scale);
            if (transpose_out) Y[(size_t)col * N_TOK + row] = val;
            else               Y[(size_t)row * HID + col] = val;
        }
    }
}

// ------------------------- flash attention v7 ----------------------------
// 256 thr (4 waves); wave owns 32 q-rows (BM=128); KVB=32 keys/tile.
// Triple-buffered LDS, 2-deep prefetch, counted vmcnt (T4).
__global__ __launch_bounds__(256, 3) void flash_kernel(
    const short* __restrict__ qh, const short* __restrict__ kh,
    const short* __restrict__ vhT,
    short* __restrict__ Opart, float* __restrict__ Mpart, float* __restrict__ Lpart,
    int nsplit)
{
    __shared__ short K_lds[3][KVB * HID];   // 3 x 8KB [key][256B], 3-bit swz
    __shared__ short V_lds[3][64 * 64];     // 3 x 8KB [vrow=d>>1][128B], 3-bit swz

    const int tid  = threadIdx.x;
    const int lane = tid & 63;
    const int wave = tid >> 6;
    const int hi   = lane >> 5;
    const int col  = lane & 31;

    const int lid = blockIdx.x;
    const int split = lid >> 7;          // [0, nsplit)
    const int qtile = lid & 127;         // [0, 128)

    const int qb = qtile * BM + wave * 32;
    const int tbase = TOT_TILES / nsplit, trem = TOT_TILES % nsplit;
    const int ntiles = tbase + (split < trem ? 1 : 0);
    const int kv0 = (tbase * split + (split < trem ? split : trem)) * KVB;

    // Q B-frags: qf[kk] = qh[qb+col][16kk + 8hi + j]
    bf16x8 qf[8];
    const short* qrow = qh + (size_t)(qb + col) * HID + 8 * hi;
#pragma unroll
    for (int kk = 0; kk < 8; ++kk)
        qf[kk] = *(const bf16x8*)(qrow + 16 * kk);

    f32x16 o[4];
#pragma unroll
    for (int nf = 0; nf < 4; ++nf)
#pragma unroll
        for (int i = 0; i < 16; ++i) o[nf][i] = 0.f;
    float m_run = -1e30f, l_run = 0.f;   // log2 domain; l per half-lane

    // --- staging source addresses (pre-swizzled global, LDS linear) ---
    const uint32_t L0 = (uint32_t)tid * 16;      // [0,4096)
    const uint32_t L1 = L0 + 4096;               // [4096,8192)
    // K: row=L>>8 (256B rows, 16 chunks), src ch = ch ^ (row&7)
    const uint32_t kr0 = L0 >> 8, kc0 = ((L0 >> 4) & 15) ^ (kr0 & 7);
    const uint32_t kr1 = L1 >> 8, kc1 = ((L1 >> 4) & 15) ^ (kr1 & 7);
    // V: vrow=L>>7 (128B rows, 8 chunks), src ch = ch ^ (vrow&7);
    //    chunk ch holds d = 2*vrow + (ch>>2), keys (ch&3)*8..+8
    const uint32_t vr0 = L0 >> 7, vch0 = ((L0 >> 4) & 7) ^ (vr0 & 7);
    const uint32_t vr1 = L1 >> 7, vch1 = ((L1 >> 4) & 7) ^ (vr1 & 7);
    const uint32_t vd0 = 2 * vr0 + (vch0 >> 2), vk0 = (vch0 & 3) * 8;
    const uint32_t vd1 = 2 * vr1 + (vch1 >> 2), vk1 = (vch1 & 3) * 8;
    const short* ks0 = kh + (size_t)(kv0 + kr0) * HID + kc0 * 8;
    const short* ks1 = kh + (size_t)(kv0 + kr1) * HID + kc1 * 8;
    const short* vs0 = vhT + (size_t)vd0 * N_TOK + kv0 + vk0;
    const short* vs1 = vhT + (size_t)vd1 * N_TOK + kv0 + vk1;

    auto stage = [&](int t, int buf) {
        gl16(ks0 + (size_t)t * (KVB * HID), &K_lds[buf][wave * 512]);
        gl16(ks1 + (size_t)t * (KVB * HID), &K_lds[buf][2048 + wave * 512]);
        gl16(vs0 + t * KVB, &V_lds[buf][wave * 512]);
        gl16(vs1 + t * KVB, &V_lds[buf][2048 + wave * 512]);
    };

    // prologue: 2-deep prefetch; wait only tile 0 (4 of 8 outstanding)
    stage(0, 0);
    stage(1, 1);
    asm volatile("s_waitcnt vmcnt(4)" ::: "memory");
    __builtin_amdgcn_s_barrier();

    for (int t = 0; t < ntiles; ++t) {
        const int cur = t % 3;
        if (t + 2 < ntiles) stage(t + 2, (t + 2) % 3);
        const short* Kc = &K_lds[cur][0];
        const short* Vc = &V_lds[cur][0];

        // ---- QK^T swapped: s0 = S[key 0..31][q=col] ----
        f32x16 s0;
#pragma unroll
        for (int i = 0; i < 16; ++i) s0[i] = 0.f;
        __builtin_amdgcn_s_setprio(1);
#pragma unroll
        for (int kk = 0; kk < 8; ++kk) {
            const int sw = ((2 * kk + hi) ^ (col & 7)) << 3;
            bf16x8 ka0 = *(const bf16x8*)(Kc + col * HID + sw);
            s0 = MFMA32(ka0, qf[kk], s0);
        }
        __builtin_amdgcn_s_setprio(0);

        // ---- tile max: in-lane tree + cross-half permlane ----
        float pm = vmax16(s0);
        {
            uint32_t ax = __builtin_bit_cast(uint32_t, pm), bx = ax;
            pswap(ax, bx);
            pm = fmaxf(__builtin_bit_cast(float, ax), __builtin_bit_cast(float, bx));
        }
        if (!__all(pm - m_run <= 11.0f)) {          // defer-max (T13)
            float mn = fmaxf(m_run, pm);
            float cf = EXP2(m_run - mn);
            l_run *= cf;
#pragma unroll
            for (int nf = 0; nf < 4; ++nf)
#pragma unroll
                for (int i = 0; i < 16; ++i) o[nf][i] *= cf;
            m_run = mn;
        }

        // ---- exp + in-register P->bf16 A-frags (T12) ----
        bf16x8 pa[2];
        {
            float e[16];
#pragma unroll
            for (int i = 0; i < 16; ++i) e[i] = EXP2(s0[i] - m_run);
            l_run += (((e[0]+e[1])+(e[2]+e[3])) + ((e[4]+e[5])+(e[6]+e[7])))
                   + (((e[8]+e[9])+(e[10]+e[11])) + ((e[12]+e[13])+(e[14]+e[15])));
            uint32_t x0 = cvtpk(e[0], e[1]),   x1 = cvtpk(e[2], e[3]);
            uint32_t x2 = cvtpk(e[4], e[5]),   x3 = cvtpk(e[6], e[7]);
            uint32_t x4 = cvtpk(e[8], e[9]),   x5 = cvtpk(e[10], e[11]);
            uint32_t x6 = cvtpk(e[12], e[13]), x7 = cvtpk(e[14], e[15]);
            pswap(x0, x2);  pswap(x1, x3);
            pswap(x4, x6);  pswap(x5, x7);
            u32x4 wA, wB;
            wA[0] = x0; wA[1] = x1; wA[2] = x2; wA[3] = x3;
            wB[0] = x4; wB[1] = x5; wB[2] = x6; wB[3] = x7;
            pa[0] = __builtin_bit_cast(bf16x8, wA);
            pa[1] = __builtin_bit_cast(bf16x8, wB);
        }

        // ---- PV: O[q][d] += P[q][key] @ V[key][d] ----
        // V frag (ks,nf): vrow = 16nf + (col>>1),
        // ch = ((col&1)*4 + 2ks+hi) ^ ((col>>1)&7)  -> lanes 0-7 tile 8 banks
        __builtin_amdgcn_s_setprio(1);
#pragma unroll
        for (int ks = 0; ks < 2; ++ks) {
#pragma unroll
            for (int nf = 0; nf < 4; ++nf) {
                const int vrow = 16 * nf + (col >> 1);
                const int vch = (((col & 1) << 2) + 2 * ks + hi) ^ ((col >> 1) & 7);
                bf16x8 vf = *(const bf16x8*)(Vc + vrow * 64 + vch * 8);
                o[nf] = MFMA32(pa[ks], vf, o[nf]);
            }
        }
        __builtin_amdgcn_s_setprio(0);

        // counted wait: keep deepest prefetch in flight (T4)
        if (t + 2 < ntiles)      asm volatile("s_waitcnt vmcnt(4)" ::: "memory");
        else if (t + 1 < ntiles) asm volatile("s_waitcnt vmcnt(0)" ::: "memory");
        __builtin_amdgcn_s_barrier();
    }

    // ---- epilogue (bf16 Opart) ----
    {
        uint32_t ax = __builtin_bit_cast(uint32_t, l_run), bx = ax;
        pswap(ax, bx);
        l_run = __builtin_bit_cast(float, ax) + __builtin_bit_cast(float, bx);
    }
    const size_t sbase = (size_t)split * N_TOK + qb;
#pragma unroll
    for (int nf = 0; nf < 4; ++nf)
#pragma unroll
        for (int r = 0; r < 16; ++r) {
            int qr = (r & 3) + 8 * (r >> 2) + 4 * hi;
            Opart[(sbase + qr) * HID + 32 * nf + col] = f2bf(o[nf][r]);
        }
    if (lane < 32) {
        Mpart[sbase + col] = m_run;
        Lpart[sbase + col] = l_run;
    }
}

// --------------- output projection with fused LSE combine ----------------
__global__ __launch_bounds__(256) void oproj_kernel(
    const short* __restrict__ Opart, const float* __restrict__ Mpart,
    const float* __restrict__ Lpart,
    const short* __restrict__ WoT, const float* __restrict__ bo,
    float* __restrict__ out, int nsplit)
{
    const int lane = threadIdx.x & 63;
    const int wave = threadIdx.x >> 6;
    const int g = lane >> 4, c = lane & 15;
    const int rowbase = blockIdx.x * 64 + wave * 16;
    const int row = rowbase + c;

    // per-row LSE merge weights
    float M = -1e30f;
    for (int s = 0; s < nsplit; ++s) M = fmaxf(M, Mpart[(size_t)s * N_TOK + row]);
    float denom = 0.f;
    for (int s = 0; s < nsplit; ++s)
        denom += EXP2(Mpart[(size_t)s * N_TOK + row] - M) * Lpart[(size_t)s * N_TOK + row];
    const float inv = 1.0f / denom;

    // weighted O accumulation (this lane's 32 d-values: kk*32 + 8g + j)
    float osum[4][8];
#pragma unroll
    for (int kk = 0; kk < 4; ++kk)
#pragma unroll
        for (int j = 0; j < 8; ++j) osum[kk][j] = 0.f;
    for (int s = 0; s < nsplit; ++s) {
        float w = EXP2(Mpart[(size_t)s * N_TOK + row] - M) * inv;
        const short* orow = Opart + ((size_t)s * N_TOK + row) * HID;
#pragma unroll
        for (int kk = 0; kk < 4; ++kk) {
            bf16x8 vv = *(const bf16x8*)(orow + kk * 32 + 8 * g);
#pragma unroll
            for (int j = 0; j < 8; ++j) osum[kk][j] += w * (float)vv[j];
        }
    }
    bf16x8 a[4];
#pragma unroll
    for (int kk = 0; kk < 4; ++kk) {
        short8 t;
#pragma unroll
        for (int j = 0; j < 8; ++j) t[j] = f2bf(osum[kk][j]);
        a[kk] = __builtin_bit_cast(bf16x8, t);
    }

    f32x4 acc[16];
#pragma unroll
    for (int nf = 0; nf < 16; ++nf) acc[nf] = (f32x4){0.f, 0.f, 0.f, 0.f};
#pragma unroll
    for (int kk = 0; kk < 4; ++kk)
#pragma unroll
        for (int nf = 0; nf < 16; ++nf) {
            bf16x8 b = *(const bf16x8*)(WoT + (size_t)(c + 16 * nf) * HID + kk * 32 + 8 * g);
            acc[nf] = MFMA16(a[kk], b, acc[nf]);
        }

#pragma unroll
    for (int nf = 0; nf < 16; ++nf) {
        int colo = c + 16 * nf;
        float bval = bo[colo];
#pragma unroll
        for (int r = 0; r < 4; ++r)
            out[(size_t)(rowbase + 4 * g + r) * OUT_DIM + colo] = acc[nf][r] + bval;
    }
}

// ------------------------- launch ----------------------------------------
extern "C" void kernel_launch(void* const* d_in, const int* in_sizes, int n_in,
                              void* d_out, int out_size, void* d_ws, size_t ws_size,
                              hipStream_t stream)
{
    (void)in_sizes; (void)n_in; (void)out_size;
    const float* q  = (const float*)d_in[0];
    const float* k  = (const float*)d_in[1];
    const float* v  = (const float*)d_in[2];
    const float* Wq = (const float*)d_in[3];
    const float* bq = (const float*)d_in[4];
    const float* Wk = (const float*)d_in[5];
    const float* bk = (const float*)d_in[6];
    const float* Wv = (const float*)d_in[7];
    const float* bvp= (const float*)d_in[8];
    const float* Wo = (const float*)d_in[9];
    const float* bo = (const float*)d_in[10];
    float* out = (float*)d_out;

    auto need = [](int ns) -> size_t {
        return (size_t)(4 * 65536)
             + (size_t)3 * N_TOK * HID * 2
             + (size_t)ns * N_TOK * HID * 2
             + (size_t)ns * N_TOK * 8
             + (size_t)64 * 1024;
    };
    int nsplit = 6;
    if (ws_size < need(6)) nsplit = 4;
    if (ws_size < need(4)) nsplit = 2;
    if (ws_size < need(2)) nsplit = 1;

    char* base = (char*)d_ws;
    size_t off = 0;
    auto alloc = [&](size_t bytes) -> void* {
        void* p = base + off;
        off = (off + bytes + 255) & ~(size_t)255;
        return p;
    };
    short* wtq = (short*)alloc(128 * 256 * 2);
    short* wtk = (short*)alloc(128 * 256 * 2);
    short* wtv = (short*)alloc(128 * 256 * 2);
    short* wto = (short*)alloc(256 * 128 * 2);
    short* qh  = (short*)alloc((size_t)N_TOK * HID * 2);
    short* khb = (short*)alloc((size_t)N_TOK * HID * 2);
    short* vhT = (short*)alloc((size_t)N_TOK * HID * 2);
    short* Opart = (short*)alloc((size_t)nsplit * N_TOK * HID * 2);
    float* Mp  = (float*)alloc((size_t)nsplit * N_TOK * 4);
    float* Lp  = (float*)alloc((size_t)nsplit * N_TOK * 4);

    // 128^-0.5 * log2(e): logits land in log2 domain for exp2-based softmax
    const float SCALE_L2E = 0.088388347648318447f * 1.4426950408889634f;

    wt4_kernel<<<512, 256, 0, stream>>>(Wq, Wk, Wv, Wo, wtq, wtk, wtv, wto);

    proj3_kernel<<<dim3(N_TOK / 64, 3), 256, 0, stream>>>(
        q, k, v, wtq, wtk, wtv, bq, bk, bvp, qh, khb, vhT, SCALE_L2E);

    flash_kernel<<<dim3(128 * nsplit), 256, 0, stream>>>(
        qh, khb, vhT, Opart, Mp, Lp, nsplit);

    oproj_kernel<<<N_TOK / 64, 256, 0, stream>>>(
        Opart, Mp, Lp, wto, bo, out, nsplit);
}